// Round 1
// baseline (1495.851 us; speedup 1.0000x reference)
//
#include <hip/hip_runtime.h>
#include <hip/hip_bf16.h>

// ---- problem constants ----
#define NW 5
#define KS 5
#define SEQ 196
#define DIM 384
#define NSUP 25        // NW*KS support images
#define NQRY 75        // query images
#define NIMG 100       // NSUP + NQRY
#define LSUP 4900      // NSUP*SEQ support rows
#define BLOCK_W 980    // KS*SEQ rows per class block
#define OPT_STEPS 15

static constexpr float TEMP_F = 0.0510310363f;
static constexpr float INV_T  = 1.0f / TEMP_F;   // ~19.5959
static constexpr float LR_F   = 0.1f;

// ---------------------------------------------------------------------------
// Kernel 1: row L2-normalize (rows of length 384). 128 threads/row.
// matches ref: v / max(||v||, 1e-8)
// ---------------------------------------------------------------------------
__global__ __launch_bounds__(128) void norm_rows(const float* __restrict__ src,
                                                 float* __restrict__ dst) {
    int row = blockIdx.x;
    const float* in  = src + (size_t)row * DIM;
    float*       out = dst + (size_t)row * DIM;
    int t = threadIdx.x;
    float x0 = in[t], x1 = in[t + 128], x2 = in[t + 256];
    float s = x0 * x0 + x1 * x1 + x2 * x2;
    #pragma unroll
    for (int off = 32; off; off >>= 1) s += __shfl_down(s, off);
    __shared__ float wsum[2];
    if ((t & 63) == 0) wsum[t >> 6] = s;
    __syncthreads();
    float tot = wsum[0] + wsum[1];
    float sc = 1.0f / fmaxf(sqrtf(tot), 1e-8f);
    out[t] = x0 * sc; out[t + 128] = x1 * sc; out[t + 256] = x2 * sc;
}

// ---------------------------------------------------------------------------
// Kernel 2: fused exp-sum GEMM.
//   Rall[img][ls] = sum_qs exp( dot(Kn[ls], Qimg[qs]) * INV_T )
// img < 25 -> support-query image (apply block mask: row-image == img -> 0)
// img >= 25 -> query image (no mask)
// Tile: 64 ls-rows x 208 qs (196 padded), KC=32 k-chunks.
// 256 thr = 16 rowgroups(x4 rows) x 16 qgroups(x16 qs).
// ---------------------------------------------------------------------------
#define KC   32
#define KROW 68     // 64 + 4 pad (row stride of transposed K tile, floats)
#define QROW 212    // 208 + 4 pad (row stride of transposed Q tile, floats)

__global__ __launch_bounds__(256) void fused_expsum(const float* __restrict__ Kn,
                                                    const float* __restrict__ Qsn,
                                                    const float* __restrict__ Qn,
                                                    float* __restrict__ Rall) {
    __shared__ __align__(16) float KT[KC * KROW];
    __shared__ __align__(16) float QT[KC * QROW];
    __shared__ float red[64 * 17];

    int t = threadIdx.x;
    int img = blockIdx.y;
    int m_base = blockIdx.x * 64;
    const float* Qimg = (img < NSUP) ? (Qsn + (size_t)img * SEQ * DIM)
                                     : (Qn + (size_t)(img - NSUP) * SEQ * DIM);
    int rg = t & 15;        // rows 4*rg .. 4*rg+3
    int qg = t >> 4;        // qs 16*qg .. 16*qg+15
    int qstart = qg * 16;

    float acc[4][16];
    #pragma unroll
    for (int r = 0; r < 4; ++r)
        #pragma unroll
        for (int c = 0; c < 16; ++c) acc[r][c] = 0.f;

    for (int kb = 0; kb < DIM; kb += KC) {
        // stage K tile (transposed): KT[kk][row]
        #pragma unroll
        for (int i = t; i < 64 * KC / 4; i += 256) {
            int row = i >> 3;
            int kk4 = (i & 7) * 4;
            float4 vv = make_float4(0.f, 0.f, 0.f, 0.f);
            int grow = m_base + row;
            if (grow < LSUP)
                vv = *(const float4*)(Kn + (size_t)grow * DIM + kb + kk4);
            KT[(kk4 + 0) * KROW + row] = vv.x;
            KT[(kk4 + 1) * KROW + row] = vv.y;
            KT[(kk4 + 2) * KROW + row] = vv.z;
            KT[(kk4 + 3) * KROW + row] = vv.w;
        }
        // stage Q tile (transposed): QT[kk][qs], qs padded to 208 with zeros
        for (int i = t; i < 208 * KC / 4; i += 256) {
            int qs = i >> 3;
            int kk4 = (i & 7) * 4;
            float4 vv = make_float4(0.f, 0.f, 0.f, 0.f);
            if (qs < SEQ)
                vv = *(const float4*)(Qimg + (size_t)qs * DIM + kb + kk4);
            QT[(kk4 + 0) * QROW + qs] = vv.x;
            QT[(kk4 + 1) * QROW + qs] = vv.y;
            QT[(kk4 + 2) * QROW + qs] = vv.z;
            QT[(kk4 + 3) * QROW + qs] = vv.w;
        }
        __syncthreads();

        #pragma unroll 4
        for (int kk = 0; kk < KC; ++kk) {
            float4 a = *(const float4*)(KT + kk * KROW + rg * 4);
            #pragma unroll
            for (int jj = 0; jj < 4; ++jj) {
                float4 q = *(const float4*)(QT + kk * QROW + qstart + jj * 4);
                #pragma unroll
                for (int c = 0; c < 4; ++c) {
                    float qc = (c == 0) ? q.x : (c == 1) ? q.y : (c == 2) ? q.z : q.w;
                    acc[0][jj * 4 + c] += a.x * qc;
                    acc[1][jj * 4 + c] += a.y * qc;
                    acc[2][jj * 4 + c] += a.z * qc;
                    acc[3][jj * 4 + c] += a.w * qc;
                }
            }
        }
        __syncthreads();
    }

    // epilogue: exp + sum over this thread's qs, then cross-group reduce
    float s_r[4] = {0.f, 0.f, 0.f, 0.f};
    #pragma unroll
    for (int j = 0; j < 16; ++j) {
        bool ok = (qstart + j) < SEQ;
        #pragma unroll
        for (int r = 0; r < 4; ++r)
            s_r[r] += ok ? __expf(acc[r][j] * INV_T) : 0.f;
    }
    #pragma unroll
    for (int r = 0; r < 4; ++r) red[(rg * 4 + r) * 17 + qg] = s_r[r];
    __syncthreads();
    if (t < 64) {
        float tot = 0.f;
        #pragma unroll
        for (int g = 0; g < 16; ++g) tot += red[t * 17 + g];
        int ls = m_base + t;
        if (ls < LSUP) {
            if (img < NSUP && (ls / SEQ) == img) tot = 0.f;  // block-diag mask
            Rall[(size_t)img * LSUP + ls] = tot;
        }
    }
}

// ---------------------------------------------------------------------------
// Kernel 3: the whole 15-step SGD on v, in ONE block (1024 thr).
//   e[ls] = exp(v[ls]/T)
//   D[b][w] = sum_{ls in block w} e[ls]*R[b][ls]     (p[b][w] = log D)
//   softmax coeff: cf[b][w] = (D/ΣD - onehot(y_b)) * (INV_T/25) / D[b][w]
//   g[ls] = e[ls] * sum_b cf[b][w(ls)] * R[b][ls];  v -= LR*g
// ---------------------------------------------------------------------------
__global__ __launch_bounds__(1024) void opt_v(const float* __restrict__ Rall,
                                              const int* __restrict__ labels,
                                              float* __restrict__ v_out) {
    __shared__ float v_s[LSUP];
    __shared__ float e_s[LSUP];
    __shared__ float D_s[125];
    __shared__ float cf_s[125];
    int t = threadIdx.x;
    for (int i = t; i < LSUP; i += 1024) v_s[i] = 0.f;
    __syncthreads();

    for (int step = 0; step < OPT_STEPS; ++step) {
        for (int i = t; i < LSUP; i += 1024) e_s[i] = __expf(v_s[i] * INV_T);
        __syncthreads();

        int bw = t >> 3, sub = t & 7;
        if (bw < 125) {
            int b = bw / 5, w = bw % 5;
            const float* Rb = Rall + (size_t)b * LSUP + w * BLOCK_W;
            const float* eb = e_s + w * BLOCK_W;
            float p = 0.f;
            for (int i = sub; i < BLOCK_W; i += 8) p += eb[i] * Rb[i];
            p += __shfl_down(p, 4, 8);
            p += __shfl_down(p, 2, 8);
            p += __shfl_down(p, 1, 8);
            if (sub == 0) D_s[bw] = p;
        }
        __syncthreads();

        if (t < NSUP) {
            int b = t;
            float Dsum = 0.f;
            #pragma unroll
            for (int w = 0; w < NW; ++w) Dsum += D_s[b * 5 + w];
            int y = labels[b];
            #pragma unroll
            for (int w = 0; w < NW; ++w) {
                float Dv = D_s[b * 5 + w];
                float sm = Dv / Dsum;
                cf_s[b * 5 + w] = (sm - (w == y ? 1.f : 0.f)) * (INV_T / 25.f) / Dv;
            }
        }
        __syncthreads();

        for (int i = t; i < LSUP; i += 1024) {
            int w = i / BLOCK_W;
            float s = 0.f;
            #pragma unroll
            for (int b = 0; b < NSUP; ++b)
                s += cf_s[b * 5 + w] * Rall[(size_t)b * LSUP + i];
            v_s[i] -= LR_F * e_s[i] * s;
        }
        __syncthreads();
    }
    for (int i = t; i < LSUP; i += 1024) v_out[i] = v_s[i];
}

// ---------------------------------------------------------------------------
// Kernel 4: final prediction. out[qb][w] = log( sum_{ls in w} e^{v/T} * P[qb][ls] )
// one block per (qb, w)
// ---------------------------------------------------------------------------
__global__ __launch_bounds__(256) void final_pred(const float* __restrict__ Rall,
                                                  const float* __restrict__ v,
                                                  float* __restrict__ out) {
    int blk = blockIdx.x;           // qb*5 + w
    int qb = blk / 5, w = blk % 5;
    const float* R  = Rall + (size_t)(NSUP + qb) * LSUP + w * BLOCK_W;
    const float* vb = v + w * BLOCK_W;
    int t = threadIdx.x;
    float p = 0.f;
    for (int i = t; i < BLOCK_W; i += 256) p += __expf(vb[i] * INV_T) * R[i];
    #pragma unroll
    for (int off = 32; off; off >>= 1) p += __shfl_down(p, off);
    __shared__ float wsum[4];
    if ((t & 63) == 0) wsum[t >> 6] = p;
    __syncthreads();
    if (t == 0) out[blk] = logf(wsum[0] + wsum[1] + wsum[2] + wsum[3]);
}

// ---------------------------------------------------------------------------
extern "C" void kernel_launch(void* const* d_in, const int* in_sizes, int n_in,
                              void* d_out, int out_size, void* d_ws, size_t ws_size,
                              hipStream_t stream) {
    const float* sup_key = (const float*)d_in[0];   // [25,196,384]
    const float* sup_qry = (const float*)d_in[1];   // [25,196,384]
    const float* qry     = (const float*)d_in[2];   // [75,196,384]
    const int*   labels  = (const int*)d_in[3];     // [25]
    float* out = (float*)d_out;                     // [75,5]

    float* ws   = (float*)d_ws;
    float* Kn   = ws;                                // 4900*384
    float* Qsn  = Kn  + (size_t)LSUP * DIM;          // 4900*384
    float* Qn   = Qsn + (size_t)LSUP * DIM;          // 14700*384
    float* Rall = Qn  + (size_t)NQRY * SEQ * DIM;    // 100*4900
    float* v    = Rall + (size_t)NIMG * LSUP;        // 4900

    norm_rows<<<LSUP, 128, 0, stream>>>(sup_key, Kn);
    norm_rows<<<LSUP, 128, 0, stream>>>(sup_qry, Qsn);
    norm_rows<<<NQRY * SEQ, 128, 0, stream>>>(qry, Qn);

    fused_expsum<<<dim3((LSUP + 63) / 64, NIMG), 256, 0, stream>>>(Kn, Qsn, Qn, Rall);

    opt_v<<<1, 1024, 0, stream>>>(Rall, labels, v);

    final_pred<<<NQRY * NW, 256, 0, stream>>>(Rall, v, out);
}

// Round 2
// 415.230 us; speedup vs baseline: 3.6025x; 3.6025x over previous
//
#include <hip/hip_runtime.h>
#include <hip/hip_bf16.h>

// ---- problem constants ----
#define NW 5
#define KS 5
#define SEQ 196
#define DIM 384
#define NSUP 25        // NW*KS support images
#define NQRY 75        // query images
#define NIMG 100       // NSUP + NQRY
#define LSUP 4900      // NSUP*SEQ support rows
#define BLOCK_W 980    // KS*SEQ rows per class block
#define OPT_STEPS 15

static constexpr float TEMP_F = 0.0510310363f;
static constexpr float INV_T  = 1.0f / TEMP_F;   // ~19.5959
static constexpr float LR_F   = 0.1f;

typedef short v8s __attribute__((ext_vector_type(8)));   // 8 x bf16 frag (4 VGPRs)
typedef float v4f __attribute__((ext_vector_type(4)));   // 4 x f32 acc

__device__ inline unsigned short f2bf(float x) {
    // round-to-nearest-even bf16 (inputs finite)
    unsigned int u = __float_as_uint(x);
    u += 0x7fffu + ((u >> 16) & 1u);
    return (unsigned short)(u >> 16);
}

// ---------------------------------------------------------------------------
// Kernel 1: row L2-normalize rows of 384, emit bf16, optional extra scale
// (scale=INV_T for the K side so the GEMM result is already C/T).
// ---------------------------------------------------------------------------
__global__ __launch_bounds__(128) void norm_rows_bf16(const float* __restrict__ src,
                                                      unsigned short* __restrict__ dst,
                                                      float scale) {
    int row = blockIdx.x;
    const float* in = src + (size_t)row * DIM;
    unsigned short* out = dst + (size_t)row * DIM;
    int t = threadIdx.x;
    float x0 = in[t], x1 = in[t + 128], x2 = in[t + 256];
    float s = x0 * x0 + x1 * x1 + x2 * x2;
    #pragma unroll
    for (int off = 32; off; off >>= 1) s += __shfl_down(s, off);
    __shared__ float wsum[2];
    if ((t & 63) == 0) wsum[t >> 6] = s;
    __syncthreads();
    float sc = scale / fmaxf(sqrtf(wsum[0] + wsum[1]), 1e-8f);
    out[t]       = f2bf(x0 * sc);
    out[t + 128] = f2bf(x1 * sc);
    out[t + 256] = f2bf(x2 * sc);
}

// ---------------------------------------------------------------------------
// Kernel 2: MFMA fused exp-sum GEMM.
//   Rall[img][ls] = sum_qs exp( (Kn[ls] . Qimg[qs]) / T )
// K rows pre-scaled by 1/T.  img<25: zero rows of support image img (mask).
// Block tile: 128 rows x 208 cols (196 padded), KC=64 bf16 stages.
// 4 waves; wave w: rows [32w,32w+32) as two 16-row MFMA tiles x 13 col-tiles.
// ---------------------------------------------------------------------------
#define MT  128
#define NTP 208
#define NTT 13
#define KCC 64
#define LDE 72    // LDS row stride in bf16 elems (64 + 8 pad)

__global__ __launch_bounds__(256, 3) void fused_expsum_mfma(
    const unsigned short* __restrict__ Kb,
    const unsigned short* __restrict__ Qsb,
    const unsigned short* __restrict__ Qb,
    float* __restrict__ Rall)
{
    __shared__ __align__(16) unsigned short Asm[MT * LDE];    // 18432 B
    __shared__ __align__(16) unsigned short Bsm[NTP * LDE];   // 29952 B

    int t = threadIdx.x;
    int img = blockIdx.y;
    int m_base = blockIdx.x * MT;
    const unsigned short* Qimg = (img < NSUP)
        ? (Qsb + (size_t)img * SEQ * DIM)
        : (Qb + (size_t)(img - NSUP) * SEQ * DIM);

    int wv = t >> 6;        // wave 0..3
    int l  = t & 63;
    int lo = l & 15;        // MFMA col / row-in-tile for frags
    int hi = l >> 4;        // k-group

    v4f acc0[NTT], acc1[NTT];
    #pragma unroll
    for (int n = 0; n < NTT; ++n) {
        acc0[n] = (v4f){0.f, 0.f, 0.f, 0.f};
        acc1[n] = (v4f){0.f, 0.f, 0.f, 0.f};
    }

    for (int kb = 0; kb < DIM; kb += KCC) {
        // stage A: 128 rows x 64 k (8 bf16 = 16B per lane-load)
        for (int i = t; i < MT * 8; i += 256) {
            int row = i >> 3, kc = i & 7;
            int grow = m_base + row;
            float4 vvv = make_float4(0.f, 0.f, 0.f, 0.f);
            if (grow < LSUP)
                vvv = *(const float4*)(Kb + (size_t)grow * DIM + kb + kc * 8);
            *(float4*)(Asm + row * LDE + kc * 8) = vvv;
        }
        // stage B: 208 rows (qs; >=196 zero) x 64 k
        for (int i = t; i < NTP * 8; i += 256) {
            int qs = i >> 3, kc = i & 7;
            float4 vvv = make_float4(0.f, 0.f, 0.f, 0.f);
            if (qs < SEQ)
                vvv = *(const float4*)(Qimg + (size_t)qs * DIM + kb + kc * 8);
            *(float4*)(Bsm + qs * LDE + kc * 8) = vvv;
        }
        __syncthreads();

        const unsigned short* Abase = Asm + (wv * 32 + lo) * LDE + hi * 8;
        const unsigned short* Bbase = Bsm + lo * LDE + hi * 8;
        #pragma unroll
        for (int kk = 0; kk < 2; ++kk) {
            v8s a0 = *(const v8s*)(Abase + kk * 32);
            v8s a1 = *(const v8s*)(Abase + 16 * LDE + kk * 32);
            #pragma unroll
            for (int n = 0; n < NTT; ++n) {
                v8s bb = *(const v8s*)(Bbase + n * 16 * LDE + kk * 32);
                acc0[n] = __builtin_amdgcn_mfma_f32_16x16x32_bf16(a0, bb, acc0[n], 0, 0, 0);
                acc1[n] = __builtin_amdgcn_mfma_f32_16x16x32_bf16(a1, bb, acc1[n], 0, 0, 0);
            }
        }
        __syncthreads();
    }

    // epilogue: exp + sum over cols. C/D layout: col=lo, row=hi*4+reg.
    float s0[4] = {0.f, 0.f, 0.f, 0.f}, s1[4] = {0.f, 0.f, 0.f, 0.f};
    #pragma unroll
    for (int n = 0; n < NTT; ++n) {
        bool ok = (n * 16 + lo) < SEQ;
        #pragma unroll
        for (int j = 0; j < 4; ++j) {
            s0[j] += ok ? __expf(acc0[n][j]) : 0.f;
            s1[j] += ok ? __expf(acc1[n][j]) : 0.f;
        }
    }
    #pragma unroll
    for (int m = 1; m < 16; m <<= 1) {
        #pragma unroll
        for (int j = 0; j < 4; ++j) {
            s0[j] += __shfl_xor(s0[j], m);
            s1[j] += __shfl_xor(s1[j], m);
        }
    }
    if (lo == 0) {
        #pragma unroll
        for (int j = 0; j < 4; ++j) {
            int r0 = m_base + wv * 32 + hi * 4 + j;
            int r1 = r0 + 16;
            if (r0 < LSUP) {
                float o = s0[j];
                if (img < NSUP && (r0 / SEQ) == img) o = 0.f;
                Rall[(size_t)img * LSUP + r0] = o;
            }
            if (r1 < LSUP) {
                float o = s1[j];
                if (img < NSUP && (r1 / SEQ) == img) o = 0.f;
                Rall[(size_t)img * LSUP + r1] = o;
            }
        }
    }
}

// ---------------------------------------------------------------------------
// Kernel 3a: init. Blocks 0..124: D_bufs[0][bw] = sum R (v=0 -> e=1).
// Blocks 125..151: zero v[4900] and D_bufs[1..15] (15*125).
// ---------------------------------------------------------------------------
__global__ __launch_bounds__(256) void opt_init(const float* __restrict__ Rall,
                                                float* __restrict__ Dbufs,
                                                float* __restrict__ v) {
    __shared__ float red[4];
    int blk = blockIdx.x, t = threadIdx.x;
    if (blk < 125) {
        int b = blk / 5, w = blk % 5;
        const float* R = Rall + (size_t)b * LSUP + w * BLOCK_W;
        float s = 0.f;
        for (int i = t; i < BLOCK_W; i += 256) s += R[i];
        #pragma unroll
        for (int m = 32; m; m >>= 1) s += __shfl_xor(s, m);
        if ((t & 63) == 0) red[t >> 6] = s;
        __syncthreads();
        if (t == 0) Dbufs[blk] = red[0] + red[1] + red[2] + red[3];
    } else {
        int i = (blk - 125) * 256 + t;
        if (i < LSUP) v[i] = 0.f;
        else if (i < LSUP + 15 * 125) Dbufs[125 + (i - LSUP)] = 0.f;
    }
}

// ---------------------------------------------------------------------------
// Kernel 3b: one SGD step. 10 blocks (5 classes x 2 halves) x 512 threads.
// Every block redundantly derives cf[b] for its class from Dprev, updates its
// 490-slice of v, and atomicAdds next-step partial D into Dnext (pre-zeroed).
// ---------------------------------------------------------------------------
__global__ __launch_bounds__(512) void opt_step(const float* __restrict__ Rall,
                                                const int* __restrict__ labels,
                                                const float* __restrict__ Dprev,
                                                float* __restrict__ Dnext,
                                                float* __restrict__ v) {
    __shared__ float red[8][NSUP];
    int blk = blockIdx.x;
    int w = blk >> 1, h = blk & 1;
    int t = threadIdx.x;

    // softmax coefficients for class w (uniform across threads)
    float cf[NSUP];
    #pragma unroll
    for (int b = 0; b < NSUP; ++b) {
        float Dsum = 0.f, Dw = 1.f;
        #pragma unroll
        for (int ww = 0; ww < 5; ++ww) {
            float d = Dprev[b * 5 + ww];
            Dsum += d;
            if (ww == w) Dw = d;
        }
        int y = labels[b];
        cf[b] = ((Dw / Dsum) - (w == y ? 1.f : 0.f)) * (INV_T / 25.f) / Dw;
    }

    int li = h * 490 + t;
    bool act = (t < 490) && (li < BLOCK_W);
    int ls = w * BLOCK_W + li;
    float Rv[NSUP];
    float e_new = 0.f;
    if (act) {
        float g = 0.f;
        #pragma unroll
        for (int b = 0; b < NSUP; ++b) {
            Rv[b] = Rall[(size_t)b * LSUP + ls];
            g += cf[b] * Rv[b];
        }
        float vv = v[ls];
        float e_old = __expf(vv * INV_T);
        vv -= LR_F * e_old * g;
        v[ls] = vv;
        e_new = __expf(vv * INV_T);
    }
    float part[NSUP];
    #pragma unroll
    for (int b = 0; b < NSUP; ++b) part[b] = act ? e_new * Rv[b] : 0.f;
    #pragma unroll
    for (int b = 0; b < NSUP; ++b) {
        #pragma unroll
        for (int m = 32; m; m >>= 1) part[b] += __shfl_xor(part[b], m);
    }
    int wave = t >> 6, lane = t & 63;
    if (lane == 0) {
        #pragma unroll
        for (int b = 0; b < NSUP; ++b) red[wave][b] = part[b];
    }
    __syncthreads();
    if (t < NSUP) {
        float s = 0.f;
        #pragma unroll
        for (int wv2 = 0; wv2 < 8; ++wv2) s += red[wv2][t];
        atomicAdd(&Dnext[t * 5 + w], s);
    }
}

// ---------------------------------------------------------------------------
// Kernel 4: out[qb][w] = log( sum_{ls in w} e^{v/T} * R[25+qb][ls] )
// ---------------------------------------------------------------------------
__global__ __launch_bounds__(256) void final_pred(const float* __restrict__ Rall,
                                                  const float* __restrict__ v,
                                                  float* __restrict__ out) {
    __shared__ float wsum[4];
    int blk = blockIdx.x;           // qb*5 + w
    int qb = blk / 5, w = blk % 5;
    const float* R  = Rall + (size_t)(NSUP + qb) * LSUP + w * BLOCK_W;
    const float* vb = v + w * BLOCK_W;
    int t = threadIdx.x;
    float p = 0.f;
    for (int i = t; i < BLOCK_W; i += 256) p += __expf(vb[i] * INV_T) * R[i];
    #pragma unroll
    for (int off = 32; off; off >>= 1) p += __shfl_down(p, off);
    if ((t & 63) == 0) wsum[t >> 6] = p;
    __syncthreads();
    if (t == 0) out[blk] = logf(wsum[0] + wsum[1] + wsum[2] + wsum[3]);
}

// ---------------------------------------------------------------------------
extern "C" void kernel_launch(void* const* d_in, const int* in_sizes, int n_in,
                              void* d_out, int out_size, void* d_ws, size_t ws_size,
                              hipStream_t stream) {
    const float* sup_key = (const float*)d_in[0];   // [25,196,384]
    const float* sup_qry = (const float*)d_in[1];   // [25,196,384]
    const float* qry     = (const float*)d_in[2];   // [75,196,384]
    const int*   labels  = (const int*)d_in[3];     // [25]
    float* out = (float*)d_out;                     // [75,5]

    char* ws = (char*)d_ws;
    size_t off = 0;
    auto take = [&](size_t bytes) {
        char* p = ws + off;
        off = (off + bytes + 255) & ~(size_t)255;
        return p;
    };
    unsigned short* Kb   = (unsigned short*)take((size_t)LSUP * DIM * 2);
    unsigned short* Qsb  = (unsigned short*)take((size_t)LSUP * DIM * 2);
    unsigned short* Qb   = (unsigned short*)take((size_t)NQRY * SEQ * DIM * 2);
    float*          Rall = (float*)take((size_t)NIMG * LSUP * 4);
    float*          v    = (float*)take((size_t)LSUP * 4);
    float*          Dbuf = (float*)take((size_t)(OPT_STEPS + 1) * 125 * 4);

    norm_rows_bf16<<<LSUP, 128, 0, stream>>>(sup_key, Kb, INV_T);
    norm_rows_bf16<<<LSUP, 128, 0, stream>>>(sup_qry, Qsb, 1.0f);
    norm_rows_bf16<<<NQRY * SEQ, 128, 0, stream>>>(qry, Qb, 1.0f);

    fused_expsum_mfma<<<dim3((LSUP + MT - 1) / MT, NIMG), 256, 0, stream>>>(Kb, Qsb, Qb, Rall);

    opt_init<<<152, 256, 0, stream>>>(Rall, Dbuf, v);
    for (int s = 0; s < OPT_STEPS; ++s)
        opt_step<<<10, 512, 0, stream>>>(Rall, labels, Dbuf + s * 125, Dbuf + (s + 1) * 125, v);

    final_pred<<<NQRY * NW, 256, 0, stream>>>(Rall, v, out);
}